// Round 10
// baseline (339.103 us; speedup 1.0000x reference)
//
#include <hip/hip_runtime.h>

// NeighConv: B=2, C=256, N=4096, K=16
// Pipeline (V never materialized, SINGLE gram sweep):
//  1) sq_kernel:     sq32[p], sq64[p] = ||x_p||^2
//  2) xt_kernel:     xt[p][c] fp32 + xh[p][c] fp16 (point-major features)
//  3) wt_kernel:     Wt[d][c] = W[c][d]
//  4) dist_kernel:   LDS-staged MFMA gram; per (query, 64-col tile) store
//                    sorted top-6 (value,index) -> t6v/t6j  [one sweep only]
//  5) collect:       per query: T = 20th smallest tile-min (slot 0);
//                    append stored entries <= T+0.5; tiles whose 6th entry
//                    <= T+0.5 are rescanned scalar-wise (rare, exact)
//  6) merge_rerank:  fp64 re-rank of survivors -> true top-16 + cosine weights
//  7) y_kernel:      Y1[p]=feat@W1^T, Y2[p]=feat@W2^T + b
//  8) final_kernel:  out[b][c][i] = max_k w_k*(Y1[nk][c]+Y2[m][c])

#define B_ 2
#define C_ 256
#define N_ 4096
#define K_ 16
#define SCAP 128
#define INF_F 3.0e38f

typedef _Float16 f16x8 __attribute__((ext_vector_type(8)));
typedef float    f32x4 __attribute__((ext_vector_type(4)));

// async global->LDS, 16B per lane; LDS dest wave-uniform base + lane*16
#define GL16(gp, lp)                                                        \
    __builtin_amdgcn_global_load_lds(                                       \
        (const __attribute__((address_space(1))) void*)(gp),                \
        (__attribute__((address_space(3))) void*)(lp), 16, 0, 0)

// ---------------- 1) squared norms ----------------
__global__ void sq_kernel(const float* __restrict__ x,
                          float* __restrict__ sq32, double* __restrict__ sq64) {
    int p = blockIdx.x * 256 + threadIdx.x;           // 0..8191
    int b = p >> 12, i = p & 4095;
    const float* xb = x + ((size_t)b << 20) + i;
    double acc = 0.0;
    #pragma unroll 8
    for (int c = 0; c < C_; ++c) {
        double v = (double)xb[(size_t)c << 12];
        acc = fma(v, v, acc);
    }
    sq64[p] = acc;
    sq32[p] = (float)acc;
}

// ---------------- 2) transpose x -> xt fp32 + xh fp16 ----------------
__global__ void xt_kernel(const float* __restrict__ x, float* __restrict__ xt,
                          _Float16* __restrict__ xh) {
    __shared__ float tile[64][65];
    int i0 = blockIdx.x * 64;
    int c0 = blockIdx.y * 64;
    int b  = blockIdx.z;
    const float* xb = x + ((size_t)b << 20);
    int tid = threadIdx.x;
    int tx = tid & 63, tyy = tid >> 6;
    for (int r = tyy; r < 64; r += 4)
        tile[r][tx] = xb[(size_t)(c0 + r) * N_ + i0 + tx];
    __syncthreads();
    float*    xtb = xt + ((size_t)b << 20);
    _Float16* xhb = xh + ((size_t)b << 20);
    for (int r = tyy; r < 64; r += 4) {
        float v = tile[tx][r];
        xtb[(size_t)(i0 + r) * C_ + c0 + tx] = v;
        xhb[(size_t)(i0 + r) * C_ + c0 + tx] = (_Float16)v;
    }
}

// ---------------- 3) transpose W -> Wt[d][c] ----------------
__global__ void wt_kernel(const float* __restrict__ W, float* __restrict__ Wt) {
    __shared__ float tile[64][65];
    int d0 = blockIdx.x * 64;
    int c0 = blockIdx.y * 64;
    int tid = threadIdx.x;
    int tx = tid & 63, tyy = tid >> 6;
    for (int r = tyy; r < 64; r += 4)
        tile[r][tx] = W[(size_t)(c0 + r) * 512 + d0 + tx];
    __syncthreads();
    for (int r = tyy; r < 64; r += 4)
        Wt[(size_t)(d0 + r) * C_ + c0 + tx] = tile[tx][r];
}

// ---------------- 4) single-sweep MFMA gram + per-tile top-6 ----------------
// block 256 = 4 waves (2x2 of 64x64), tile 128(i) x 128(j), BK=64 halfs.
// Proven R5 inner loop (73us): A+B LDS dbuf, XOR swizzle byte^((row&7)<<4)
// applied to global SOURCE (gload_lds writes linearly) and to ds_reads.
// Epilogue: per query, per 64-col tile: sorted top-6 (lex (v,idx)) via
// per-lane sort4 + 6 butterfly-argmin rounds, stored to t6v/t6j.
__launch_bounds__(256, 2)
__global__ void dist_kernel(const _Float16* __restrict__ xh,
                            const float* __restrict__ sq32,
                            float* __restrict__ t6v,
                            unsigned short* __restrict__ t6j) {
    __shared__ _Float16 As[2][128][64];
    __shared__ _Float16 Bs[2][128][64];

    int jt = blockIdx.x, it = blockIdx.y, b = blockIdx.z;
    int tid = threadIdx.x;
    int w = tid >> 6, l = tid & 63;
    int wr = w >> 1, wc = w & 1;
    int lr = l & 15, lg = l >> 4;
    const _Float16* xb = xh + ((size_t)b << 20);
    int rA0 = it * 128, rB0 = jt * 128;

    int rsub = l >> 3;                          // 0..7
    int cb   = (l & 7) << 4;                    // 0..112 bytes

    auto STAGE = [&](int bf, int k0) {
        #pragma unroll
        for (int tt = 0; tt < 4; ++tt) {
            int rloc = w * 32 + tt * 8 + rsub;                 // 0..127
            int srch = (cb ^ ((rloc & 7) << 4)) >> 1;          // halfs
            GL16(xb + (size_t)(rA0 + rloc) * C_ + k0 + srch, &As[bf][w * 32 + tt * 8][0]);
            GL16(xb + (size_t)(rB0 + rloc) * C_ + k0 + srch, &Bs[bf][w * 32 + tt * 8][0]);
        }
    };

    f32x4 acc[4][4];
    #pragma unroll
    for (int mi = 0; mi < 4; ++mi)
        #pragma unroll
        for (int ni = 0; ni < 4; ++ni)
            acc[mi][ni] = (f32x4){0.f, 0.f, 0.f, 0.f};

    STAGE(0, 0);
    __syncthreads();
    #pragma unroll
    for (int kt = 0; kt < 4; ++kt) {
        int cur = kt & 1;
        if (kt < 3) STAGE(cur ^ 1, (kt + 1) * 64);
        #pragma unroll
        for (int kk = 0; kk < 2; ++kk) {
            int kh = kk * 32 + lg * 8;
            f16x8 af[4], bf4[4];
            #pragma unroll
            for (int mi = 0; mi < 4; ++mi) {
                int r = wr * 64 + mi * 16 + lr;
                af[mi] = *(const f16x8*)&As[cur][r][kh ^ ((r & 7) << 3)];
            }
            #pragma unroll
            for (int ni = 0; ni < 4; ++ni) {
                int r = wc * 64 + ni * 16 + lr;
                bf4[ni] = *(const f16x8*)&Bs[cur][r][kh ^ ((r & 7) << 3)];
            }
            #pragma unroll
            for (int mi = 0; mi < 4; ++mi)
                #pragma unroll
                for (int ni = 0; ni < 4; ++ni)
                    acc[mi][ni] = __builtin_amdgcn_mfma_f32_16x16x32_f16(
                        af[mi], bf4[ni], acc[mi][ni], 0, 0, 0);
        }
        __syncthreads();
    }

    int bN = b << 12;
    int tj = jt * 2 + wc;                         // 64-col tile id 0..63
    float sjv[4];
    #pragma unroll
    for (int ni = 0; ni < 4; ++ni)
        sjv[ni] = sq32[bN + jt * 128 + wc * 64 + ni * 16 + lr];

    // per (mi, r): 4 queries in parallel (one per 16-lane lg-group)
    #pragma unroll
    for (int mi = 0; mi < 4; ++mi) {
        #pragma unroll
        for (int r = 0; r < 4; ++r) {
            float hv0, hv1, hv2, hv3; int hj0, hj1, hj2, hj3;
            hv0 = sjv[0] - 2.0f * acc[mi][0][r]; hj0 = jt * 128 + wc * 64 + 0  + lr;
            hv1 = sjv[1] - 2.0f * acc[mi][1][r]; hj1 = jt * 128 + wc * 64 + 16 + lr;
            hv2 = sjv[2] - 2.0f * acc[mi][2][r]; hj2 = jt * 128 + wc * 64 + 32 + lr;
            hv3 = sjv[3] - 2.0f * acc[mi][3][r]; hj3 = jt * 128 + wc * 64 + 48 + lr;
            // sort4 ascending lex (v, j)
            #define CSWP(a, b, ja, jb)                                         \
                { bool sw = (b < a) || (b == a && jb < ja);                    \
                  float tv = a; int tj2 = ja;                                  \
                  a = sw ? b : a;  ja = sw ? jb : ja;                          \
                  b = sw ? tv : b; jb = sw ? tj2 : jb; }
            CSWP(hv0, hv1, hj0, hj1); CSWP(hv2, hv3, hj2, hj3);
            CSWP(hv0, hv2, hj0, hj2); CSWP(hv1, hv3, hj1, hj3);
            CSWP(hv1, hv2, hj1, hj2);
            #undef CSWP
            float ov[6]; int oj[6];
            #pragma unroll
            for (int rd = 0; rd < 6; ++rd) {
                float wv = hv0; int wj = hj0;
                #pragma unroll
                for (int mask = 1; mask <= 8; mask <<= 1) {
                    float o = __shfl_xor(wv, mask);
                    int  oi = __shfl_xor(wj, mask);
                    if (o < wv || (o == wv && oi < wj)) { wv = o; wj = oi; }
                }
                ov[rd] = wv; oj[rd] = wj;
                if (hj0 == wj) {                 // owner pops (idx unique)
                    hv0 = hv1; hj0 = hj1; hv1 = hv2; hj1 = hj2;
                    hv2 = hv3; hj2 = hj3; hv3 = INF_F; hj3 = 0x7fffffff;
                }
            }
            if (lr == 0) {
                int qg = bN + it * 128 + wr * 64 + lg * 4 + mi * 16 + r;
                size_t base6 = ((size_t)qg * 64 + tj) * 6;
                #pragma unroll
                for (int rd = 0; rd < 6; ++rd) {
                    t6v[base6 + rd] = ov[rd];
                    t6j[base6 + rd] = (unsigned short)oj[rd];
                }
            }
        }
    }
}

// ---------------- 5) collect: threshold + candidate append (+rare rescan) ----------------
// block 256 = 4 waves, one query per wave; lane l <-> 64-col tile l.
__global__ void collect_kernel(const float* __restrict__ t6v,
                               const unsigned short* __restrict__ t6j,
                               const _Float16* __restrict__ xh,
                               const float* __restrict__ sq32,
                               int* __restrict__ svj, int* __restrict__ cntg) {
    __shared__ float sv[4][64];
    __shared__ float sT[4];
    int tid = threadIdx.x;
    int wv4 = tid >> 6, l = tid & 63;
    int q = blockIdx.x * 4 + wv4;                 // global query 0..8191
    int b = q >> 12, bN = b << 12;

    size_t base6 = ((size_t)q * 64 + l) * 6;
    float v[6]; int j6[6];
    #pragma unroll
    for (int k = 0; k < 6; ++k) {
        v[k]  = t6v[base6 + k];
        j6[k] = (int)t6j[base6 + k];
    }

    sv[wv4][l] = v[0];
    __syncthreads();
    int rank = 0;
    for (int o = 0; o < 64; ++o) {
        float ov = sv[wv4][o];
        rank += (ov < v[0]) || (ov == v[0] && o < l);
    }
    if (rank == 19) sT[wv4] = v[0];
    __syncthreads();
    float T5 = sT[wv4] + 0.5f;

    int cnt = 0;
    #pragma unroll
    for (int k = 0; k < 6; ++k) cnt += (v[k] <= T5) ? 1 : 0;   // sorted -> prefix
    bool flag = (v[5] <= T5);                     // possible hidden 7th

    int off = cnt;
    #pragma unroll
    for (int s = 1; s < 64; s <<= 1) {
        int n = __shfl_up(off, s);
        if (l >= s) off += n;
    }
    int pos = off - cnt;
    int total = __shfl(off, 63);
    for (int k = 0; k < cnt; ++k)
        if (pos + k < SCAP) svj[(size_t)q * SCAP + pos + k] = j6[k];

    unsigned long long fb = __ballot(flag);
    if (fb != 0ULL) {                             // rare exact-completion path
        const _Float16* qrow = xh + ((size_t)q << 8);
        while (fb) {
            int tf = (int)__ffsll(fb) - 1; fb &= fb - 1;
            int jg = tf * 64 + l;                 // batch-local col
            const _Float16* jrow = xh + (((size_t)(bN + jg)) << 8);
            float dot = 0.f;
            #pragma unroll 4
            for (int c = 0; c < C_; c += 8) {
                f16x8 a = *(const f16x8*)(qrow + c);
                f16x8 bb = *(const f16x8*)(jrow + c);
                #pragma unroll
                for (int e = 0; e < 8; ++e)
                    dot = fmaf((float)a[e], (float)bb[e], dot);
            }
            float vv = sq32[bN + jg] - 2.0f * dot;
            bool dup = false;
            size_t tb = ((size_t)q * 64 + tf) * 6;
            #pragma unroll
            for (int k = 0; k < 6; ++k) dup |= ((int)t6j[tb + k] == jg);
            bool add = (vv <= T5 + 0.0625f) && !dup;
            int o2 = add ? 1 : 0;
            #pragma unroll
            for (int s = 1; s < 64; s <<= 1) {
                int n = __shfl_up(o2, s);
                if (l >= s) o2 += n;
            }
            int p2 = total + o2 - (add ? 1 : 0);
            if (add && p2 < SCAP) svj[(size_t)q * SCAP + p2] = jg;
            total += __shfl(o2, 63);
        }
    }
    if (l == 0) cntg[q] = total < SCAP ? total : SCAP;
}

// ---------------- 6) fp64 re-rank of survivors + weights ----------------
__global__ void merge_rerank(const int* __restrict__ svj, const int* __restrict__ cntg,
                             const float* __restrict__ xt,
                             const double* __restrict__ sq64,
                             int* __restrict__ nidx, float* __restrict__ wgt) {
    __shared__ double d64[32][SCAP];
    int tid = threadIdx.x;
    int pl = tid >> 3, c8 = tid & 7;
    int m = (blockIdx.x << 5) + pl;
    int b = m >> 12;
    int cnt = cntg[m]; if (cnt > SCAP) cnt = SCAP;
    const float* rm = xt + ((size_t)m << 8);
    for (int cc = c8; cc < cnt; cc += 8) {
        int j = svj[(size_t)m * SCAP + cc];
        int n = (b << 12) + j;
        const float* rn = xt + ((size_t)n << 8);
        double acc = 0.0;
        #pragma unroll 8
        for (int c = 0; c < C_; c += 4) {
            float4 a4 = *(const float4*)(rm + c);
            float4 b4 = *(const float4*)(rn + c);
            acc = fma((double)a4.x, (double)b4.x, acc);
            acc = fma((double)a4.y, (double)b4.y, acc);
            acc = fma((double)a4.z, (double)b4.z, acc);
            acc = fma((double)a4.w, (double)b4.w, acc);
        }
        d64[pl][cc] = sq64[n] - 2.0 * acc;
    }
    __syncthreads();
    if (tid < 32) {
        int mm = (blockIdx.x << 5) + tid;
        int bb = mm >> 12;
        int cn = cntg[mm]; if (cn > SCAP) cn = SCAP;
        double td[K_]; int ti[K_];
        #pragma unroll
        for (int k = 0; k < K_; ++k) { td[k] = 1.0e300; ti[k] = 0; }
        for (int cc = 0; cc < cn; ++cc) {
            double d = d64[tid][cc];
            int j = svj[(size_t)mm * SCAP + cc];
            #pragma unroll
            for (int s = 0; s < K_; ++s) {            // sorted bubble-insert, strict <
                bool lt = d < td[s];
                double od = td[s]; int oi = ti[s];
                td[s] = lt ? d : od;  ti[s] = lt ? j : oi;
                d = lt ? od : d;      j = lt ? oi : j;
            }
        }
        double sqm = sq64[mm];
        double rdm = sqrt(sqm);
        #pragma unroll
        for (int k = 0; k < K_; ++k) {
            int n = (bb << 12) + ti[k];
            double sqn = sq64[n];
            double dot = 0.5 * (sqn - td[k]);
            double w = dot / (sqrt(sqn) * rdm);
            nidx[mm * K_ + k] = n;
            wgt[mm * K_ + k]  = (float)w;
        }
    }
}

// ---------------- 7) Y1 = feat@W1^T ; Y2 = feat@W2^T + b ----------------
#define YKC 32
__launch_bounds__(256, 2)
__global__ void y_kernel(const float* __restrict__ x, const float* __restrict__ Wt,
                         const float* __restrict__ bias,
                         float* __restrict__ Y1, float* __restrict__ Y2) {
    __shared__ float af[YKC][128];
    __shared__ float wf[YKC][128];
    int p0  = blockIdx.x << 7;
    int oc0 = blockIdx.y << 6;
    int b   = blockIdx.z;
    const float* xb = x + ((size_t)b << 20);
    int tid = threadIdx.x, tx = tid & 15, ty = tid >> 4;
    int tx4 = tx << 2, ty4 = ty << 2;
    float acc[8][8];
    #pragma unroll
    for (int a = 0; a < 8; ++a)
        #pragma unroll
        for (int b2 = 0; b2 < 8; ++b2) acc[a][b2] = 0.f;

    for (int cc0 = 0; cc0 < C_; cc0 += YKC) {
        __syncthreads();
        for (int e = tid; e < YKC * 128; e += 256) {
            int d = e >> 7, q = e & 127;
            af[d][q] = xb[(size_t)(cc0 + d) * N_ + p0 + q];
            int row = (q < 64) ? (cc0 + d) : (C_ + cc0 + d);
            wf[d][q] = Wt[(size_t)row * C_ + oc0 + (q & 63)];
        }
        __syncthreads();
        #pragma unroll 8
        for (int d = 0; d < YKC; ++d) {
            float4 a0 = *(const float4*)&af[d][ty4];
            float4 a1 = *(const float4*)&af[d][64 + ty4];
            float4 w0 = *(const float4*)&wf[d][tx4];
            float4 w1 = *(const float4*)&wf[d][64 + tx4];
            float pa[8] = {a0.x, a0.y, a0.z, a0.w, a1.x, a1.y, a1.z, a1.w};
            float wa[8] = {w0.x, w0.y, w0.z, w0.w, w1.x, w1.y, w1.z, w1.w};
            #pragma unroll
            for (int a = 0; a < 8; ++a)
                #pragma unroll
                for (int b2 = 0; b2 < 8; ++b2)
                    acc[a][b2] = fmaf(pa[a], wa[b2], acc[a][b2]);
        }
    }
    float4 bv = *(const float4*)&bias[oc0 + tx4];
    #pragma unroll
    for (int ha = 0; ha < 2; ++ha) {
        #pragma unroll
        for (int a = 0; a < 4; ++a) {
            int pg = (b << 12) + p0 + ha * 64 + ty4 + a;
            float4 o1, o2;
            o1.x = acc[ha * 4 + a][0]; o1.y = acc[ha * 4 + a][1];
            o1.z = acc[ha * 4 + a][2]; o1.w = acc[ha * 4 + a][3];
            o2.x = acc[ha * 4 + a][4] + bv.x; o2.y = acc[ha * 4 + a][5] + bv.y;
            o2.z = acc[ha * 4 + a][6] + bv.z; o2.w = acc[ha * 4 + a][7] + bv.w;
            *(float4*)&Y1[(size_t)pg * C_ + oc0 + tx4] = o1;
            *(float4*)&Y2[(size_t)pg * C_ + oc0 + tx4] = o2;
        }
    }
}

// ---------------- 8) weighted max epilogue ----------------
__global__ void final_kernel(const float* __restrict__ Y1, const float* __restrict__ Y2,
                             const int* __restrict__ nidx, const float* __restrict__ wgt,
                             float* __restrict__ out) {
    __shared__ int   snk[K_];
    __shared__ float swt[K_];
    int m = blockIdx.x;
    int c = threadIdx.x;
    if (c < K_) { snk[c] = nidx[m * K_ + c]; swt[c] = wgt[m * K_ + c]; }
    __syncthreads();
    float y2 = Y2[((size_t)m << 8) + c];
    float acc = -INF_F;
    #pragma unroll
    for (int k = 0; k < K_; ++k) {
        float v = swt[k] * (Y1[((size_t)snk[k] << 8) + c] + y2);
        acc = fmaxf(acc, v);
    }
    int b = m >> 12, i = m & 4095;
    out[(((size_t)b << 8) + c) * N_ + i] = acc;
}

extern "C" void kernel_launch(void* const* d_in, const int* in_sizes, int n_in,
                              void* d_out, int out_size, void* d_ws, size_t ws_size,
                              hipStream_t stream) {
    const float* x    = (const float*)d_in[0];
    const float* W    = (const float*)d_in[1];
    const float* bias = (const float*)d_in[2];
    float* out = (float*)d_out;

    float* ws = (float*)d_ws;
    size_t off = 0;
    float*  sq32 = ws + off;            off += 8192;
    double* sq64 = (double*)(ws + off); off += 16384;
    float*  Wt   = ws + off;            off += 131072;
    float*  wgt  = ws + off;            off += 131072;
    int*    nidx = (int*)(ws + off);    off += 131072;
    int*    cntg = (int*)(ws + off);    off += 8192;
    size_t svj_off = off;
    int*    svj  = (int*)(ws + off);    off += 1048576;    // 8192 x 128
    float*  xt   = ws + off;            off += 2097152;    // 8 MB
    _Float16* xh = (_Float16*)(ws + off); off += 1048576;  // 4 MB (2M halfs)
    float*  t6v  = ws + off;            off += 3145728;    // 8192x64x6 f32
    unsigned short* t6j = (unsigned short*)(ws + off); off += 1572864;
    // Y1/Y2 reuse svj+xt / xt-end+xh regions (dead after merge_rerank)
    float*  Y1   = ws + svj_off;
    float*  Y2   = Y1 + 2097152;

    sq_kernel<<<32, 256, 0, stream>>>(x, sq32, sq64);
    xt_kernel<<<dim3(64, 4, 2), 256, 0, stream>>>(x, xt, xh);
    wt_kernel<<<dim3(8, 4, 1), 256, 0, stream>>>(W, Wt);

    dist_kernel<<<dim3(32, 32, 2), 256, 0, stream>>>(xh, sq32, t6v, t6j);
    collect_kernel<<<2048, 256, 0, stream>>>(t6v, t6j, xh, sq32, svj, cntg);

    merge_rerank<<<256, 256, 0, stream>>>(svj, cntg, xt, sq64, nidx, wgt);
    y_kernel<<<dim3(32, 4, 2), 256, 0, stream>>>(x, Wt, bias, Y1, Y2);
    final_kernel<<<8192, 256, 0, stream>>>(Y1, Y2, nidx, wgt, out);
}

// Round 11
// 224.954 us; speedup vs baseline: 1.5074x; 1.5074x over previous
//
#include <hip/hip_runtime.h>

// NeighConv: B=2, C=256, N=4096, K=16
// Pipeline (V never materialized, SINGLE gram sweep, cheap LDS epilogue):
//  1) sq_kernel:     sq32[p], sq64[p] = ||x_p||^2
//  2) xt_kernel:     xt[p][c] fp32 + xh[p][c] fp16 (point-major features)
//  3) wt_kernel:     Wt[d][c] = W[c][d]
//  4) dist_kernel:   LDS-staged MFMA gram (R5 inner loop); epilogue dumps each
//                    wave's 64x64 V block to LDS (transposed, swizzled) and
//                    each lane scans its row -> sorted top-4 per (q, 64col-tile)
//  5) collect:       per query: T = 20th smallest tile-min (slot 0) + 0.5;
//                    append stored entries <= T; tiles whose 4th entry <= T
//                    are rescanned scalar-wise (rare, exact, dedup'd)
//  6) merge_rerank:  fp64 re-rank of survivors -> true top-16 + cosine weights
//  7) y_kernel:      Y1[p]=feat@W1^T, Y2[p]=feat@W2^T + b
//  8) final_kernel:  out[b][c][i] = max_k w_k*(Y1[nk][c]+Y2[m][c])

#define B_ 2
#define C_ 256
#define N_ 4096
#define K_ 16
#define SCAP 128
#define INF_F 3.0e38f

typedef _Float16 f16x8 __attribute__((ext_vector_type(8)));
typedef float    f32x4 __attribute__((ext_vector_type(4)));

// async global->LDS, 16B per lane; LDS dest wave-uniform base + lane*16
#define GL16(gp, lp)                                                        \
    __builtin_amdgcn_global_load_lds(                                       \
        (const __attribute__((address_space(1))) void*)(gp),                \
        (__attribute__((address_space(3))) void*)(lp), 16, 0, 0)

// ---------------- 1) squared norms ----------------
__global__ void sq_kernel(const float* __restrict__ x,
                          float* __restrict__ sq32, double* __restrict__ sq64) {
    int p = blockIdx.x * 256 + threadIdx.x;           // 0..8191
    int b = p >> 12, i = p & 4095;
    const float* xb = x + ((size_t)b << 20) + i;
    double acc = 0.0;
    #pragma unroll 8
    for (int c = 0; c < C_; ++c) {
        double v = (double)xb[(size_t)c << 12];
        acc = fma(v, v, acc);
    }
    sq64[p] = acc;
    sq32[p] = (float)acc;
}

// ---------------- 2) transpose x -> xt fp32 + xh fp16 ----------------
__global__ void xt_kernel(const float* __restrict__ x, float* __restrict__ xt,
                          _Float16* __restrict__ xh) {
    __shared__ float tile[64][65];
    int i0 = blockIdx.x * 64;
    int c0 = blockIdx.y * 64;
    int b  = blockIdx.z;
    const float* xb = x + ((size_t)b << 20);
    int tid = threadIdx.x;
    int tx = tid & 63, tyy = tid >> 6;
    for (int r = tyy; r < 64; r += 4)
        tile[r][tx] = xb[(size_t)(c0 + r) * N_ + i0 + tx];
    __syncthreads();
    float*    xtb = xt + ((size_t)b << 20);
    _Float16* xhb = xh + ((size_t)b << 20);
    for (int r = tyy; r < 64; r += 4) {
        float v = tile[tx][r];
        xtb[(size_t)(i0 + r) * C_ + c0 + tx] = v;
        xhb[(size_t)(i0 + r) * C_ + c0 + tx] = (_Float16)v;
    }
}

// ---------------- 3) transpose W -> Wt[d][c] ----------------
__global__ void wt_kernel(const float* __restrict__ W, float* __restrict__ Wt) {
    __shared__ float tile[64][65];
    int d0 = blockIdx.x * 64;
    int c0 = blockIdx.y * 64;
    int tid = threadIdx.x;
    int tx = tid & 63, tyy = tid >> 6;
    for (int r = tyy; r < 64; r += 4)
        tile[r][tx] = W[(size_t)(c0 + r) * 512 + d0 + tx];
    __syncthreads();
    for (int r = tyy; r < 64; r += 4)
        Wt[(size_t)(d0 + r) * C_ + c0 + tx] = tile[tx][r];
}

// ---------------- 4) single-sweep MFMA gram + per-tile top-4 (LDS scan) ----------------
// block 256 = 4 waves (2x2 of 64x64), tile 128(i) x 128(j), BK=64 halfs.
// Proven R5 inner loop: A+B LDS dbuf, XOR swizzle byte^((row&7)<<4) applied to
// global SOURCE (gload_lds writes linearly) and to ds_reads.
// Epilogue: As/Bs are dead after the K-loop -> reuse as 4 x 16KB per-wave
// scratch. V^T stored swizzled (elem r ^ ((c&7)<<3)); lane l scans row l.
__launch_bounds__(256, 2)
__global__ void dist_kernel(const _Float16* __restrict__ xh,
                            const float* __restrict__ sq32,
                            float* __restrict__ t4v,
                            unsigned short* __restrict__ t4j) {
    __shared__ alignas(16) _Float16 As[2][128][64];
    __shared__ alignas(16) _Float16 Bs[2][128][64];

    int jt = blockIdx.x, it = blockIdx.y, b = blockIdx.z;
    int tid = threadIdx.x;
    int w = tid >> 6, l = tid & 63;
    int wr = w >> 1, wc = w & 1;
    int lr = l & 15, lg = l >> 4;
    const _Float16* xb = xh + ((size_t)b << 20);
    int rA0 = it * 128, rB0 = jt * 128;

    int rsub = l >> 3;                          // 0..7
    int cbyte = (l & 7) << 4;                   // 0..112 bytes

    auto STAGE = [&](int bf, int k0) {
        #pragma unroll
        for (int tt = 0; tt < 4; ++tt) {
            int rloc = w * 32 + tt * 8 + rsub;                 // 0..127
            int srch = (cbyte ^ ((rloc & 7) << 4)) >> 1;       // halfs
            GL16(xb + (size_t)(rA0 + rloc) * C_ + k0 + srch, &As[bf][w * 32 + tt * 8][0]);
            GL16(xb + (size_t)(rB0 + rloc) * C_ + k0 + srch, &Bs[bf][w * 32 + tt * 8][0]);
        }
    };

    f32x4 acc[4][4];
    #pragma unroll
    for (int mi = 0; mi < 4; ++mi)
        #pragma unroll
        for (int ni = 0; ni < 4; ++ni)
            acc[mi][ni] = (f32x4){0.f, 0.f, 0.f, 0.f};

    STAGE(0, 0);
    __syncthreads();
    #pragma unroll
    for (int kt = 0; kt < 4; ++kt) {
        int cur = kt & 1;
        if (kt < 3) STAGE(cur ^ 1, (kt + 1) * 64);
        #pragma unroll
        for (int kk = 0; kk < 2; ++kk) {
            int kh = kk * 32 + lg * 8;
            f16x8 af[4], bf4[4];
            #pragma unroll
            for (int mi = 0; mi < 4; ++mi) {
                int r = wr * 64 + mi * 16 + lr;
                af[mi] = *(const f16x8*)&As[cur][r][kh ^ ((r & 7) << 3)];
            }
            #pragma unroll
            for (int ni = 0; ni < 4; ++ni) {
                int r = wc * 64 + ni * 16 + lr;
                bf4[ni] = *(const f16x8*)&Bs[cur][r][kh ^ ((r & 7) << 3)];
            }
            #pragma unroll
            for (int mi = 0; mi < 4; ++mi)
                #pragma unroll
                for (int ni = 0; ni < 4; ++ni)
                    acc[mi][ni] = __builtin_amdgcn_mfma_f32_16x16x32_f16(
                        af[mi], bf4[ni], acc[mi][ni], 0, 0, 0);
        }
        __syncthreads();                        // last iter: all LDS reads retired
    }

    // ---- epilogue: per-row top-4 of this wave's 64x64 V block ----
    int bN = b << 12;
    float sjv[4];
    #pragma unroll
    for (int ni = 0; ni < 4; ++ni)
        sjv[ni] = sq32[bN + jt * 128 + wc * 64 + ni * 16 + lr];

    float* vb = (float*)&As[0][0][0] + w * 4096;        // 16KB per wave
    #pragma unroll
    for (int mi = 0; mi < 4; ++mi)
        #pragma unroll
        for (int ni = 0; ni < 4; ++ni) {
            int c  = ni * 16 + lr;
            int rb = (mi * 16 + lg * 4) ^ ((c & 7) << 3);
            f32x4 vv;
            #pragma unroll
            for (int r = 0; r < 4; ++r)
                vv[r] = sjv[ni] - 2.0f * acc[mi][ni][r];
            *(f32x4*)&vb[c * 64 + rb] = vv;             // V^T, swizzled
        }
    asm volatile("s_waitcnt lgkmcnt(0)" ::: "memory");  // wave-local visibility
    __builtin_amdgcn_sched_barrier(0);

    float v0 = INF_F, v1 = INF_F, v2 = INF_F, v3 = INF_F;
    int j0 = 0, j1 = 0, j2 = 0, j3 = 0;
    #pragma unroll
    for (int c = 0; c < 64; ++c) {
        float v = vb[c * 64 + (l ^ ((c & 7) << 3))];
        bool in = v < v3;                               // strict: lowest-c wins ties
        v3 = in ? v : v3;  j3 = in ? c : j3;
        { bool s = v3 < v2; float t = v2; int tj2 = j2;
          v2 = s ? v3 : v2; v3 = s ? t : v3; j2 = s ? j3 : j2; j3 = s ? tj2 : j3; }
        { bool s = v2 < v1; float t = v1; int tj2 = j1;
          v1 = s ? v2 : v1; v2 = s ? t : v2; j1 = s ? j2 : j1; j2 = s ? tj2 : j2; }
        { bool s = v1 < v0; float t = v0; int tj2 = j0;
          v0 = s ? v1 : v0; v1 = s ? t : v1; j0 = s ? j1 : j0; j1 = s ? tj2 : j1; }
    }
    int tj = jt * 2 + wc;
    int q  = bN + it * 128 + wr * 64 + l;
    int jb = jt * 128 + wc * 64;
    size_t ob = ((size_t)tj * 8192 + q) * 4;            // [tile][query] layout
    *(float4*)&t4v[ob] = make_float4(v0, v1, v2, v3);
    ushort4 js;
    js.x = (unsigned short)(jb + j0); js.y = (unsigned short)(jb + j1);
    js.z = (unsigned short)(jb + j2); js.w = (unsigned short)(jb + j3);
    *(ushort4*)&t4j[ob] = js;
}

// ---------------- 5) collect: threshold + candidate append (+rare rescan) ----------------
// block 256 = 4 waves, one query per wave; lane l <-> 64-col tile l.
__global__ void collect_kernel(const float* __restrict__ t4v,
                               const unsigned short* __restrict__ t4j,
                               const _Float16* __restrict__ xh,
                               const float* __restrict__ sq32,
                               int* __restrict__ svj, int* __restrict__ cntg) {
    __shared__ float sv[4][64];
    __shared__ float sT[4];
    int tid = threadIdx.x;
    int wv4 = tid >> 6, l = tid & 63;
    int q = blockIdx.x * 4 + wv4;                 // global query 0..8191
    int b = q >> 12, bN = b << 12;

    size_t base = ((size_t)l * 8192 + q) * 4;
    float4 vf = *(const float4*)&t4v[base];
    ushort4 uf = *(const ushort4*)&t4j[base];
    float v[4] = {vf.x, vf.y, vf.z, vf.w};
    int  j4[4] = {(int)uf.x, (int)uf.y, (int)uf.z, (int)uf.w};

    sv[wv4][l] = v[0];
    __syncthreads();
    int rank = 0;
    for (int o = 0; o < 64; ++o) {
        float ov = sv[wv4][o];
        rank += (ov < v[0]) || (ov == v[0] && o < l);
    }
    if (rank == 19) sT[wv4] = v[0];
    __syncthreads();
    float T5 = sT[wv4] + 0.5f;

    int cnt = 0;
    #pragma unroll
    for (int k = 0; k < 4; ++k) cnt += (v[k] <= T5) ? 1 : 0;   // sorted -> prefix
    bool flag = (v[3] <= T5);                     // possible hidden 5th

    int off = cnt;
    #pragma unroll
    for (int s = 1; s < 64; s <<= 1) {
        int n = __shfl_up(off, s);
        if (l >= s) off += n;
    }
    int pos = off - cnt;
    int total = __shfl(off, 63);
    for (int k = 0; k < cnt; ++k)
        if (pos + k < SCAP) svj[(size_t)q * SCAP + pos + k] = j4[k];

    unsigned long long fb = __ballot(flag);
    if (fb != 0ULL) {                             // rare exact-completion path
        const _Float16* qrow = xh + ((size_t)q << 8);
        while (fb) {
            int tf = (int)__ffsll(fb) - 1; fb &= fb - 1;
            int jg = tf * 64 + l;                 // batch-local col
            const _Float16* jrow = xh + (((size_t)(bN + jg)) << 8);
            float dot = 0.f;
            #pragma unroll 4
            for (int c = 0; c < C_; c += 8) {
                f16x8 a = *(const f16x8*)(qrow + c);
                f16x8 bb = *(const f16x8*)(jrow + c);
                #pragma unroll
                for (int e = 0; e < 8; ++e)
                    dot = fmaf((float)a[e], (float)bb[e], dot);
            }
            float vv = sq32[bN + jg] - 2.0f * dot;
            bool dup = false;
            size_t tb = ((size_t)tf * 8192 + q) * 4;
            #pragma unroll
            for (int k = 0; k < 4; ++k) dup |= ((int)t4j[tb + k] == jg);
            bool add = (vv <= T5 + 0.0625f) && !dup;
            int o2 = add ? 1 : 0;
            #pragma unroll
            for (int s = 1; s < 64; s <<= 1) {
                int n = __shfl_up(o2, s);
                if (l >= s) o2 += n;
            }
            int p2 = total + o2 - (add ? 1 : 0);
            if (add && p2 < SCAP) svj[(size_t)q * SCAP + p2] = jg;
            total += __shfl(o2, 63);
        }
    }
    if (l == 0) cntg[q] = total < SCAP ? total : SCAP;
}

// ---------------- 6) fp64 re-rank of survivors + weights ----------------
__global__ void merge_rerank(const int* __restrict__ svj, const int* __restrict__ cntg,
                             const float* __restrict__ xt,
                             const double* __restrict__ sq64,
                             int* __restrict__ nidx, float* __restrict__ wgt) {
    __shared__ double d64[32][SCAP];
    int tid = threadIdx.x;
    int pl = tid >> 3, c8 = tid & 7;
    int m = (blockIdx.x << 5) + pl;
    int b = m >> 12;
    int cnt = cntg[m]; if (cnt > SCAP) cnt = SCAP;
    const float* rm = xt + ((size_t)m << 8);
    for (int cc = c8; cc < cnt; cc += 8) {
        int j = svj[(size_t)m * SCAP + cc];
        int n = (b << 12) + j;
        const float* rn = xt + ((size_t)n << 8);
        double acc = 0.0;
        #pragma unroll 8
        for (int c = 0; c < C_; c += 4) {
            float4 a4 = *(const float4*)(rm + c);
            float4 b4 = *(const float4*)(rn + c);
            acc = fma((double)a4.x, (double)b4.x, acc);
            acc = fma((double)a4.y, (double)b4.y, acc);
            acc = fma((double)a4.z, (double)b4.z, acc);
            acc = fma((double)a4.w, (double)b4.w, acc);
        }
        d64[pl][cc] = sq64[n] - 2.0 * acc;
    }
    __syncthreads();
    if (tid < 32) {
        int mm = (blockIdx.x << 5) + tid;
        int bb = mm >> 12;
        int cn = cntg[mm]; if (cn > SCAP) cn = SCAP;
        double td[K_]; int ti[K_];
        #pragma unroll
        for (int k = 0; k < K_; ++k) { td[k] = 1.0e300; ti[k] = 0; }
        for (int cc = 0; cc < cn; ++cc) {
            double d = d64[tid][cc];
            int j = svj[(size_t)mm * SCAP + cc];
            #pragma unroll
            for (int s = 0; s < K_; ++s) {            // sorted bubble-insert, strict <
                bool lt = d < td[s];
                double od = td[s]; int oi = ti[s];
                td[s] = lt ? d : od;  ti[s] = lt ? j : oi;
                d = lt ? od : d;      j = lt ? oi : j;
            }
        }
        double sqm = sq64[mm];
        double rdm = sqrt(sqm);
        #pragma unroll
        for (int k = 0; k < K_; ++k) {
            int n = (bb << 12) + ti[k];
            double sqn = sq64[n];
            double dot = 0.5 * (sqn - td[k]);
            double w = dot / (sqrt(sqn) * rdm);
            nidx[mm * K_ + k] = n;
            wgt[mm * K_ + k]  = (float)w;
        }
    }
}

// ---------------- 7) Y1 = feat@W1^T ; Y2 = feat@W2^T + b ----------------
#define YKC 32
__launch_bounds__(256, 2)
__global__ void y_kernel(const float* __restrict__ x, const float* __restrict__ Wt,
                         const float* __restrict__ bias,
                         float* __restrict__ Y1, float* __restrict__ Y2) {
    __shared__ float af[YKC][128];
    __shared__ float wf[YKC][128];
    int p0  = blockIdx.x << 7;
    int oc0 = blockIdx.y << 6;
    int b   = blockIdx.z;
    const float* xb = x + ((size_t)b << 20);
    int tid = threadIdx.x, tx = tid & 15, ty = tid >> 4;
    int tx4 = tx << 2, ty4 = ty << 2;
    float acc[8][8];
    #pragma unroll
    for (int a = 0; a < 8; ++a)
        #pragma unroll
        for (int b2 = 0; b2 < 8; ++b2) acc[a][b2] = 0.f;

    for (int cc0 = 0; cc0 < C_; cc0 += YKC) {
        __syncthreads();
        for (int e = tid; e < YKC * 128; e += 256) {
            int d = e >> 7, q = e & 127;
            af[d][q] = xb[(size_t)(cc0 + d) * N_ + p0 + q];
            int row = (q < 64) ? (cc0 + d) : (C_ + cc0 + d);
            wf[d][q] = Wt[(size_t)row * C_ + oc0 + (q & 63)];
        }
        __syncthreads();
        #pragma unroll 8
        for (int d = 0; d < YKC; ++d) {
            float4 a0 = *(const float4*)&af[d][ty4];
            float4 a1 = *(const float4*)&af[d][64 + ty4];
            float4 w0 = *(const float4*)&wf[d][tx4];
            float4 w1 = *(const float4*)&wf[d][64 + tx4];
            float pa[8] = {a0.x, a0.y, a0.z, a0.w, a1.x, a1.y, a1.z, a1.w};
            float wa[8] = {w0.x, w0.y, w0.z, w0.w, w1.x, w1.y, w1.z, w1.w};
            #pragma unroll
            for (int a = 0; a < 8; ++a)
                #pragma unroll
                for (int b2 = 0; b2 < 8; ++b2)
                    acc[a][b2] = fmaf(pa[a], wa[b2], acc[a][b2]);
        }
    }
    float4 bv = *(const float4*)&bias[oc0 + tx4];
    #pragma unroll
    for (int ha = 0; ha < 2; ++ha) {
        #pragma unroll
        for (int a = 0; a < 4; ++a) {
            int pg = (b << 12) + p0 + ha * 64 + ty4 + a;
            float4 o1, o2;
            o1.x = acc[ha * 4 + a][0]; o1.y = acc[ha * 4 + a][1];
            o1.z = acc[ha * 4 + a][2]; o1.w = acc[ha * 4 + a][3];
            o2.x = acc[ha * 4 + a][4] + bv.x; o2.y = acc[ha * 4 + a][5] + bv.y;
            o2.z = acc[ha * 4 + a][6] + bv.z; o2.w = acc[ha * 4 + a][7] + bv.w;
            *(float4*)&Y1[(size_t)pg * C_ + oc0 + tx4] = o1;
            *(float4*)&Y2[(size_t)pg * C_ + oc0 + tx4] = o2;
        }
    }
}

// ---------------- 8) weighted max epilogue ----------------
__global__ void final_kernel(const float* __restrict__ Y1, const float* __restrict__ Y2,
                             const int* __restrict__ nidx, const float* __restrict__ wgt,
                             float* __restrict__ out) {
    __shared__ int   snk[K_];
    __shared__ float swt[K_];
    int m = blockIdx.x;
    int c = threadIdx.x;
    if (c < K_) { snk[c] = nidx[m * K_ + c]; swt[c] = wgt[m * K_ + c]; }
    __syncthreads();
    float y2 = Y2[((size_t)m << 8) + c];
    float acc = -INF_F;
    #pragma unroll
    for (int k = 0; k < K_; ++k) {
        float v = swt[k] * (Y1[((size_t)snk[k] << 8) + c] + y2);
        acc = fmaxf(acc, v);
    }
    int b = m >> 12, i = m & 4095;
    out[(((size_t)b << 8) + c) * N_ + i] = acc;
}

extern "C" void kernel_launch(void* const* d_in, const int* in_sizes, int n_in,
                              void* d_out, int out_size, void* d_ws, size_t ws_size,
                              hipStream_t stream) {
    const float* x    = (const float*)d_in[0];
    const float* W    = (const float*)d_in[1];
    const float* bias = (const float*)d_in[2];
    float* out = (float*)d_out;

    float* ws = (float*)d_ws;
    size_t off = 0;
    float*  sq32 = ws + off;            off += 8192;
    double* sq64 = (double*)(ws + off); off += 16384;
    float*  Wt   = ws + off;            off += 131072;
    float*  wgt  = ws + off;            off += 131072;
    int*    nidx = (int*)(ws + off);    off += 131072;
    int*    cntg = (int*)(ws + off);    off += 8192;
    size_t svj_off = off;
    int*    svj  = (int*)(ws + off);    off += 1048576;    // 8192 x 128
    float*  xt   = ws + off;            off += 2097152;    // 8 MB
    _Float16* xh = (_Float16*)(ws + off); off += 1048576;  // 4 MB (2M halfs)
    float*  t4v  = ws + off;            off += 2097152;    // 64 x 8192 x 4 f32
    unsigned short* t4j = (unsigned short*)(ws + off); off += 1048576; // same, ushort
    // Y1/Y2 reuse svj+xt / xt-end+xh regions (dead after merge_rerank / collect)
    float*  Y1   = ws + svj_off;
    float*  Y2   = Y1 + 2097152;

    sq_kernel<<<32, 256, 0, stream>>>(x, sq32, sq64);
    xt_kernel<<<dim3(64, 4, 2), 256, 0, stream>>>(x, xt, xh);
    wt_kernel<<<dim3(8, 4, 1), 256, 0, stream>>>(W, Wt);

    dist_kernel<<<dim3(32, 32, 2), 256, 0, stream>>>(xh, sq32, t4v, t4j);
    collect_kernel<<<2048, 256, 0, stream>>>(t4v, t4j, xh, sq32, svj, cntg);

    merge_rerank<<<256, 256, 0, stream>>>(svj, cntg, xt, sq64, nidx, wgt);
    y_kernel<<<dim3(32, 4, 2), 256, 0, stream>>>(x, Wt, bias, Y1, Y2);
    final_kernel<<<8192, 256, 0, stream>>>(Y1, Y2, nidx, wgt, out);
}

// Round 12
// 195.550 us; speedup vs baseline: 1.7341x; 1.1504x over previous
//
#include <hip/hip_runtime.h>

// NeighConv: B=2, C=256, N=4096, K=16
// Pipeline (V never materialized, SINGLE gram sweep, cheap LDS epilogue):
//  1) sq_kernel:     sq32[p], sq64[p] = ||x_p||^2
//  2) xt_kernel:     xt[p][c] fp32 + xh[p][c] fp16 (point-major features)
//  3) wh_kernel:     Wh[r][c] fp16: r<256 -> W[r][c] (W1), r>=256 -> W[r-256][256+c] (W2)
//  4) dist_kernel:   LDS-staged MFMA gram; epilogue dumps each wave's 64x64 V
//                    block to LDS (transposed, swizzled), lane scans its row
//                    -> sorted top-4 per (q, 64col-tile)
//  5) collect:       per query: T = 20th smallest tile-min (slot 0) + 0.5;
//                    append stored entries <= T; tiles whose 4th entry <= T
//                    are rescanned scalar-wise (rare, exact, dedup'd)
//  6) merge_rerank:  fp64 re-rank of survivors -> true top-16 + cosine weights
//  7) yh_kernel:     MFMA fp16: Yh[p][0:256]=feat@W1^T, Yh[p][256:512]=feat@W2^T+b
//  8) final_kernel:  out[b][c][i] = max_k w_k*(Yh[nk][c]+Yh[m][256+c])

#define B_ 2
#define C_ 256
#define N_ 4096
#define K_ 16
#define SCAP 128
#define INF_F 3.0e38f

typedef _Float16 f16x8 __attribute__((ext_vector_type(8)));
typedef float    f32x4 __attribute__((ext_vector_type(4)));

// async global->LDS, 16B per lane; LDS dest wave-uniform base + lane*16
#define GL16(gp, lp)                                                        \
    __builtin_amdgcn_global_load_lds(                                       \
        (const __attribute__((address_space(1))) void*)(gp),                \
        (__attribute__((address_space(3))) void*)(lp), 16, 0, 0)

// ---------------- 1) squared norms ----------------
__global__ void sq_kernel(const float* __restrict__ x,
                          float* __restrict__ sq32, double* __restrict__ sq64) {
    int p = blockIdx.x * 256 + threadIdx.x;           // 0..8191
    int b = p >> 12, i = p & 4095;
    const float* xb = x + ((size_t)b << 20) + i;
    double acc = 0.0;
    #pragma unroll 8
    for (int c = 0; c < C_; ++c) {
        double v = (double)xb[(size_t)c << 12];
        acc = fma(v, v, acc);
    }
    sq64[p] = acc;
    sq32[p] = (float)acc;
}

// ---------------- 2) transpose x -> xt fp32 + xh fp16 ----------------
__global__ void xt_kernel(const float* __restrict__ x, float* __restrict__ xt,
                          _Float16* __restrict__ xh) {
    __shared__ float tile[64][65];
    int i0 = blockIdx.x * 64;
    int c0 = blockIdx.y * 64;
    int b  = blockIdx.z;
    const float* xb = x + ((size_t)b << 20);
    int tid = threadIdx.x;
    int tx = tid & 63, tyy = tid >> 6;
    for (int r = tyy; r < 64; r += 4)
        tile[r][tx] = xb[(size_t)(c0 + r) * N_ + i0 + tx];
    __syncthreads();
    float*    xtb = xt + ((size_t)b << 20);
    _Float16* xhb = xh + ((size_t)b << 20);
    for (int r = tyy; r < 64; r += 4) {
        float v = tile[tx][r];
        xtb[(size_t)(i0 + r) * C_ + c0 + tx] = v;
        xhb[(size_t)(i0 + r) * C_ + c0 + tx] = (_Float16)v;
    }
}

// ---------------- 3) W -> fp16 in [outchan][c] layout (W1 rows 0..255, W2 256..511) ----------------
__global__ void wh_kernel(const float* __restrict__ W, _Float16* __restrict__ Wh) {
    int r = blockIdx.x;                               // 0..511
    int c = threadIdx.x;                              // 0..255
    float v = (r < 256) ? W[(size_t)r * 512 + c]
                        : W[(size_t)(r - 256) * 512 + 256 + c];
    Wh[(size_t)r * 256 + c] = (_Float16)v;
}

// ---------------- 4) single-sweep MFMA gram + per-tile top-4 (LDS scan) ----------------
// block 256 = 4 waves (2x2 of 64x64), tile 128(i) x 128(j), BK=64 halfs.
// Proven R5 inner loop: A+B LDS dbuf, XOR swizzle byte^((row&7)<<4) applied to
// global SOURCE (gload_lds writes linearly) and to ds_reads.
// Epilogue: As/Bs dead after K-loop -> reuse as 4 x 16KB per-wave scratch.
// V^T stored swizzled (elem r ^ ((c&7)<<3)); lane l scans row l.
__launch_bounds__(256, 2)
__global__ void dist_kernel(const _Float16* __restrict__ xh,
                            const float* __restrict__ sq32,
                            float* __restrict__ t4v,
                            unsigned short* __restrict__ t4j) {
    __shared__ alignas(16) _Float16 As[2][128][64];
    __shared__ alignas(16) _Float16 Bs[2][128][64];

    int jt = blockIdx.x, it = blockIdx.y, b = blockIdx.z;
    int tid = threadIdx.x;
    int w = tid >> 6, l = tid & 63;
    int wr = w >> 1, wc = w & 1;
    int lr = l & 15, lg = l >> 4;
    const _Float16* xb = xh + ((size_t)b << 20);
    int rA0 = it * 128, rB0 = jt * 128;

    int rsub = l >> 3;                          // 0..7
    int cbyte = (l & 7) << 4;                   // 0..112 bytes

    auto STAGE = [&](int bf, int k0) {
        #pragma unroll
        for (int tt = 0; tt < 4; ++tt) {
            int rloc = w * 32 + tt * 8 + rsub;                 // 0..127
            int srch = (cbyte ^ ((rloc & 7) << 4)) >> 1;       // halfs
            GL16(xb + (size_t)(rA0 + rloc) * C_ + k0 + srch, &As[bf][w * 32 + tt * 8][0]);
            GL16(xb + (size_t)(rB0 + rloc) * C_ + k0 + srch, &Bs[bf][w * 32 + tt * 8][0]);
        }
    };

    f32x4 acc[4][4];
    #pragma unroll
    for (int mi = 0; mi < 4; ++mi)
        #pragma unroll
        for (int ni = 0; ni < 4; ++ni)
            acc[mi][ni] = (f32x4){0.f, 0.f, 0.f, 0.f};

    STAGE(0, 0);
    __syncthreads();
    #pragma unroll
    for (int kt = 0; kt < 4; ++kt) {
        int cur = kt & 1;
        if (kt < 3) STAGE(cur ^ 1, (kt + 1) * 64);
        #pragma unroll
        for (int kk = 0; kk < 2; ++kk) {
            int kh = kk * 32 + lg * 8;
            f16x8 af[4], bf4[4];
            #pragma unroll
            for (int mi = 0; mi < 4; ++mi) {
                int r = wr * 64 + mi * 16 + lr;
                af[mi] = *(const f16x8*)&As[cur][r][kh ^ ((r & 7) << 3)];
            }
            #pragma unroll
            for (int ni = 0; ni < 4; ++ni) {
                int r = wc * 64 + ni * 16 + lr;
                bf4[ni] = *(const f16x8*)&Bs[cur][r][kh ^ ((r & 7) << 3)];
            }
            #pragma unroll
            for (int mi = 0; mi < 4; ++mi)
                #pragma unroll
                for (int ni = 0; ni < 4; ++ni)
                    acc[mi][ni] = __builtin_amdgcn_mfma_f32_16x16x32_f16(
                        af[mi], bf4[ni], acc[mi][ni], 0, 0, 0);
        }
        __syncthreads();                        // last iter: all LDS reads retired
    }

    // ---- epilogue: per-row top-4 of this wave's 64x64 V block ----
    int bN = b << 12;
    float sjv[4];
    #pragma unroll
    for (int ni = 0; ni < 4; ++ni)
        sjv[ni] = sq32[bN + jt * 128 + wc * 64 + ni * 16 + lr];

    float* vb = (float*)&As[0][0][0] + w * 4096;        // 16KB per wave
    #pragma unroll
    for (int mi = 0; mi < 4; ++mi)
        #pragma unroll
        for (int ni = 0; ni < 4; ++ni) {
            int c  = ni * 16 + lr;
            int rb = (mi * 16 + lg * 4) ^ ((c & 7) << 3);
            f32x4 vv;
            #pragma unroll
            for (int r = 0; r < 4; ++r)
                vv[r] = sjv[ni] - 2.0f * acc[mi][ni][r];
            *(f32x4*)&vb[c * 64 + rb] = vv;             // V^T, swizzled
        }
    asm volatile("s_waitcnt lgkmcnt(0)" ::: "memory");  // wave-local visibility
    __builtin_amdgcn_sched_barrier(0);

    float v0 = INF_F, v1 = INF_F, v2 = INF_F, v3 = INF_F;
    int j0 = 0, j1 = 0, j2 = 0, j3 = 0;
    #pragma unroll
    for (int c = 0; c < 64; ++c) {
        float v = vb[c * 64 + (l ^ ((c & 7) << 3))];
        bool in = v < v3;                               // strict: lowest-c wins ties
        v3 = in ? v : v3;  j3 = in ? c : j3;
        { bool s = v3 < v2; float t = v2; int tj2 = j2;
          v2 = s ? v3 : v2; v3 = s ? t : v3; j2 = s ? j3 : j2; j3 = s ? tj2 : j3; }
        { bool s = v2 < v1; float t = v1; int tj2 = j1;
          v1 = s ? v2 : v1; v2 = s ? t : v2; j1 = s ? j2 : j1; j2 = s ? tj2 : j2; }
        { bool s = v1 < v0; float t = v0; int tj2 = j0;
          v0 = s ? v1 : v0; v1 = s ? t : v1; j0 = s ? j1 : j0; j1 = s ? tj2 : j1; }
    }
    int tj = jt * 2 + wc;
    int q  = bN + it * 128 + wr * 64 + l;
    int jb = jt * 128 + wc * 64;
    size_t ob = ((size_t)tj * 8192 + q) * 4;            // [tile][query] layout
    *(float4*)&t4v[ob] = make_float4(v0, v1, v2, v3);
    ushort4 js;
    js.x = (unsigned short)(jb + j0); js.y = (unsigned short)(jb + j1);
    js.z = (unsigned short)(jb + j2); js.w = (unsigned short)(jb + j3);
    *(ushort4*)&t4j[ob] = js;
}

// ---------------- 5) collect: threshold + candidate append (+rare rescan) ----------------
// block 256 = 4 waves, one query per wave; lane l <-> 64-col tile l.
__global__ void collect_kernel(const float* __restrict__ t4v,
                               const unsigned short* __restrict__ t4j,
                               const _Float16* __restrict__ xh,
                               const float* __restrict__ sq32,
                               int* __restrict__ svj, int* __restrict__ cntg) {
    __shared__ float sv[4][64];
    __shared__ float sT[4];
    int tid = threadIdx.x;
    int wv4 = tid >> 6, l = tid & 63;
    int q = blockIdx.x * 4 + wv4;                 // global query 0..8191
    int b = q >> 12, bN = b << 12;

    size_t base = ((size_t)l * 8192 + q) * 4;
    float4 vf = *(const float4*)&t4v[base];
    ushort4 uf = *(const ushort4*)&t4j[base];
    float v[4] = {vf.x, vf.y, vf.z, vf.w};
    int  j4[4] = {(int)uf.x, (int)uf.y, (int)uf.z, (int)uf.w};

    sv[wv4][l] = v[0];
    __syncthreads();
    int rank = 0;
    for (int o = 0; o < 64; ++o) {
        float ov = sv[wv4][o];
        rank += (ov < v[0]) || (ov == v[0] && o < l);
    }
    if (rank == 19) sT[wv4] = v[0];
    __syncthreads();
    float T5 = sT[wv4] + 0.5f;

    int cnt = 0;
    #pragma unroll
    for (int k = 0; k < 4; ++k) cnt += (v[k] <= T5) ? 1 : 0;   // sorted -> prefix
    bool flag = (v[3] <= T5);                     // possible hidden 5th

    int off = cnt;
    #pragma unroll
    for (int s = 1; s < 64; s <<= 1) {
        int n = __shfl_up(off, s);
        if (l >= s) off += n;
    }
    int pos = off - cnt;
    int total = __shfl(off, 63);
    for (int k = 0; k < cnt; ++k)
        if (pos + k < SCAP) svj[(size_t)q * SCAP + pos + k] = j4[k];

    unsigned long long fb = __ballot(flag);
    if (fb != 0ULL) {                             // rare exact-completion path
        const _Float16* qrow = xh + ((size_t)q << 8);
        while (fb) {
            int tf = (int)__ffsll(fb) - 1; fb &= fb - 1;
            int jg = tf * 64 + l;                 // batch-local col
            const _Float16* jrow = xh + (((size_t)(bN + jg)) << 8);
            float dot = 0.f;
            #pragma unroll 4
            for (int c = 0; c < C_; c += 8) {
                f16x8 a = *(const f16x8*)(qrow + c);
                f16x8 bb = *(const f16x8*)(jrow + c);
                #pragma unroll
                for (int e = 0; e < 8; ++e)
                    dot = fmaf((float)a[e], (float)bb[e], dot);
            }
            float vv = sq32[bN + jg] - 2.0f * dot;
            bool dup = false;
            size_t tb = ((size_t)tf * 8192 + q) * 4;
            #pragma unroll
            for (int k = 0; k < 4; ++k) dup |= ((int)t4j[tb + k] == jg);
            bool add = (vv <= T5 + 0.0625f) && !dup;
            int o2 = add ? 1 : 0;
            #pragma unroll
            for (int s = 1; s < 64; s <<= 1) {
                int n = __shfl_up(o2, s);
                if (l >= s) o2 += n;
            }
            int p2 = total + o2 - (add ? 1 : 0);
            if (add && p2 < SCAP) svj[(size_t)q * SCAP + p2] = jg;
            total += __shfl(o2, 63);
        }
    }
    if (l == 0) cntg[q] = total < SCAP ? total : SCAP;
}

// ---------------- 6) fp64 re-rank of survivors + weights ----------------
// block 256 = 8 queries x 32 threads; grid 1024 (4x the TLP of the old 256x8)
__global__ void merge_rerank(const int* __restrict__ svj, const int* __restrict__ cntg,
                             const float* __restrict__ xt,
                             const double* __restrict__ sq64,
                             int* __restrict__ nidx, float* __restrict__ wgt) {
    __shared__ double d64[8][SCAP];
    int tid = threadIdx.x;
    int pl = tid >> 5, c32 = tid & 31;
    int m = (blockIdx.x << 3) + pl;
    int b = m >> 12;
    int cnt = cntg[m]; if (cnt > SCAP) cnt = SCAP;
    const float* rm = xt + ((size_t)m << 8);
    for (int cc = c32; cc < cnt; cc += 32) {
        int j = svj[(size_t)m * SCAP + cc];
        int n = (b << 12) + j;
        const float* rn = xt + ((size_t)n << 8);
        double acc = 0.0;
        #pragma unroll 8
        for (int c = 0; c < C_; c += 4) {
            float4 a4 = *(const float4*)(rm + c);
            float4 b4 = *(const float4*)(rn + c);
            acc = fma((double)a4.x, (double)b4.x, acc);
            acc = fma((double)a4.y, (double)b4.y, acc);
            acc = fma((double)a4.z, (double)b4.z, acc);
            acc = fma((double)a4.w, (double)b4.w, acc);
        }
        d64[pl][cc] = sq64[n] - 2.0 * acc;
    }
    __syncthreads();
    if (tid < 8) {
        int mm = (blockIdx.x << 3) + tid;
        int bb = mm >> 12;
        int cn = cntg[mm]; if (cn > SCAP) cn = SCAP;
        double td[K_]; int ti[K_];
        #pragma unroll
        for (int k = 0; k < K_; ++k) { td[k] = 1.0e300; ti[k] = 0; }
        for (int cc = 0; cc < cn; ++cc) {
            double d = d64[tid][cc];
            int j = svj[(size_t)mm * SCAP + cc];
            #pragma unroll
            for (int s = 0; s < K_; ++s) {            // sorted bubble-insert, strict <
                bool lt = d < td[s];
                double od = td[s]; int oi = ti[s];
                td[s] = lt ? d : od;  ti[s] = lt ? j : oi;
                d = lt ? od : d;      j = lt ? oi : j;
            }
        }
        double sqm = sq64[mm];
        double rdm = sqrt(sqm);
        #pragma unroll
        for (int k = 0; k < K_; ++k) {
            int n = (bb << 12) + ti[k];
            double sqn = sq64[n];
            double dot = 0.5 * (sqn - td[k]);
            double w = dot / (sqrt(sqn) * rdm);
            nidx[mm * K_ + k] = n;
            wgt[mm * K_ + k]  = (float)w;
        }
    }
}

// ---------------- 7) Yh via MFMA fp16: Yh[p][0:256]=Y1, [256:512]=Y2+b ----------------
// Same structure as dist K-loop: A = xh rows (points), B = Wh rows (out chans).
// grid (4, 64): jt over 512 Wh rows, it over 8192 points.
__launch_bounds__(256, 2)
__global__ void yh_kernel(const _Float16* __restrict__ xh,
                          const _Float16* __restrict__ Wh,
                          const float* __restrict__ bias,
                          _Float16* __restrict__ Yh) {
    __shared__ alignas(16) _Float16 As[2][128][64];
    __shared__ alignas(16) _Float16 Bs[2][128][64];

    int jt = blockIdx.x, it = blockIdx.y;
    int tid = threadIdx.x;
    int w = tid >> 6, l = tid & 63;
    int wr = w >> 1, wc = w & 1;
    int lr = l & 15, lg = l >> 4;
    int rA0 = it * 128, rB0 = jt * 128;

    int rsub = l >> 3;
    int cbyte = (l & 7) << 4;

    auto STAGE = [&](int bf, int k0) {
        #pragma unroll
        for (int tt = 0; tt < 4; ++tt) {
            int rloc = w * 32 + tt * 8 + rsub;
            int srch = (cbyte ^ ((rloc & 7) << 4)) >> 1;
            GL16(xh + (size_t)(rA0 + rloc) * C_ + k0 + srch, &As[bf][w * 32 + tt * 8][0]);
            GL16(Wh + (size_t)(rB0 + rloc) * C_ + k0 + srch, &Bs[bf][w * 32 + tt * 8][0]);
        }
    };

    f32x4 acc[4][4];
    #pragma unroll
    for (int mi = 0; mi < 4; ++mi)
        #pragma unroll
        for (int ni = 0; ni < 4; ++ni)
            acc[mi][ni] = (f32x4){0.f, 0.f, 0.f, 0.f};

    STAGE(0, 0);
    __syncthreads();
    #pragma unroll
    for (int kt = 0; kt < 4; ++kt) {
        int cur = kt & 1;
        if (kt < 3) STAGE(cur ^ 1, (kt + 1) * 64);
        #pragma unroll
        for (int kk = 0; kk < 2; ++kk) {
            int kh = kk * 32 + lg * 8;
            f16x8 af[4], bf4[4];
            #pragma unroll
            for (int mi = 0; mi < 4; ++mi) {
                int r = wr * 64 + mi * 16 + lr;
                af[mi] = *(const f16x8*)&As[cur][r][kh ^ ((r & 7) << 3)];
            }
            #pragma unroll
            for (int ni = 0; ni < 4; ++ni) {
                int r = wc * 64 + ni * 16 + lr;
                bf4[ni] = *(const f16x8*)&Bs[cur][r][kh ^ ((r & 7) << 3)];
            }
            #pragma unroll
            for (int mi = 0; mi < 4; ++mi)
                #pragma unroll
                for (int ni = 0; ni < 4; ++ni)
                    acc[mi][ni] = __builtin_amdgcn_mfma_f32_16x16x32_f16(
                        af[mi], bf4[ni], acc[mi][ni], 0, 0, 0);
        }
        __syncthreads();
    }

    int colbase = jt * 128 + wc * 64;             // wave-uniform
    bool isY2 = colbase >= 256;
    float bv[4];
    #pragma unroll
    for (int ni = 0; ni < 4; ++ni)
        bv[ni] = isY2 ? bias[colbase - 256 + ni * 16 + lr] : 0.f;

    #pragma unroll
    for (int mi = 0; mi < 4; ++mi)
        #pragma unroll
        for (int r = 0; r < 4; ++r) {
            int p = it * 128 + wr * 64 + mi * 16 + lg * 4 + r;
            #pragma unroll
            for (int ni = 0; ni < 4; ++ni)
                Yh[(size_t)p * 512 + colbase + ni * 16 + lr] =
                    (_Float16)(acc[mi][ni][r] + bv[ni]);
        }
}

// ---------------- 8) weighted max epilogue (fp16 Yh) ----------------
__global__ void final_kernel(const _Float16* __restrict__ Yh,
                             const int* __restrict__ nidx, const float* __restrict__ wgt,
                             float* __restrict__ out) {
    __shared__ int   snk[K_];
    __shared__ float swt[K_];
    int m = blockIdx.x;
    int c = threadIdx.x;
    if (c < K_) { snk[c] = nidx[m * K_ + c]; swt[c] = wgt[m * K_ + c]; }
    __syncthreads();
    float y2 = (float)Yh[(size_t)m * 512 + 256 + c];
    float acc = -INF_F;
    #pragma unroll
    for (int k = 0; k < K_; ++k) {
        float v = swt[k] * ((float)Yh[(size_t)snk[k] * 512 + c] + y2);
        acc = fmaxf(acc, v);
    }
    int b = m >> 12, i = m & 4095;
    out[(((size_t)b << 8) + c) * N_ + i] = acc;
}

extern "C" void kernel_launch(void* const* d_in, const int* in_sizes, int n_in,
                              void* d_out, int out_size, void* d_ws, size_t ws_size,
                              hipStream_t stream) {
    const float* x    = (const float*)d_in[0];
    const float* W    = (const float*)d_in[1];
    const float* bias = (const float*)d_in[2];
    float* out = (float*)d_out;

    float* ws = (float*)d_ws;
    size_t off = 0;
    float*  sq32 = ws + off;            off += 8192;
    double* sq64 = (double*)(ws + off); off += 16384;
    float*  wgt  = ws + off;            off += 131072;
    int*    nidx = (int*)(ws + off);    off += 131072;
    int*    cntg = (int*)(ws + off);    off += 8192;
    size_t svj_off = off;
    int*    svj  = (int*)(ws + off);    off += 1048576;    // 8192 x 128
    float*  xt   = ws + off;            off += 2097152;    // 8 MB
    _Float16* xh = (_Float16*)(ws + off); off += 1048576;  // 4 MB (2M halfs)
    float*  t4v  = ws + off;            off += 2097152;    // 64 x 8192 x 4 f32
    unsigned short* t4j = (unsigned short*)(ws + off); off += 1048576;
    _Float16* Wh = (_Float16*)(ws + off); off += 65536;    // 512x256 halfs
    // Yh (8192x512 fp16 = 2M f-equiv) overlays svj+xt (dead after merge)
    _Float16* Yh = (_Float16*)(ws + svj_off);

    sq_kernel<<<32, 256, 0, stream>>>(x, sq32, sq64);
    xt_kernel<<<dim3(64, 4, 2), 256, 0, stream>>>(x, xt, xh);
    wh_kernel<<<512, 256, 0, stream>>>(W, Wh);

    dist_kernel<<<dim3(32, 32, 2), 256, 0, stream>>>(xh, sq32, t4v, t4j);
    collect_kernel<<<2048, 256, 0, stream>>>(t4v, t4j, xh, sq32, svj, cntg);

    merge_rerank<<<1024, 256, 0, stream>>>(svj, cntg, xt, sq64, nidx, wgt);
    yh_kernel<<<dim3(4, 64, 1), 256, 0, stream>>>(xh, Wh, bias, Yh);
    final_kernel<<<8192, 256, 0, stream>>>(Yh, nidx, wgt, out);
}

// Round 13
// 169.738 us; speedup vs baseline: 1.9978x; 1.1521x over previous
//
#include <hip/hip_runtime.h>

// NeighConv: B=2, C=256, N=4096, K=16
// Pipeline (V never materialized, SINGLE gram sweep, cheap LDS epilogue):
//  1) sq_kernel:     sq32[p], sq64[p] = ||x_p||^2
//  2) xt_kernel:     xt[p][c] fp32 + xh[p][c] fp16 (point-major features)
//  3) wh_kernel:     Wh[r][c] fp16: r<256 -> W[r][c] (W1), r>=256 -> W[r-256][256+c] (W2)
//  4) dist_kernel:   LDS-staged MFMA gram; epilogue dumps each wave's 64x64 V
//                    block to LDS (transposed, swizzled), lane scans its row
//                    -> sorted top-4 per (q, 64col-tile)
//  5) collect:       per query: T = 20th smallest tile-min (slot 0) + 0.5;
//                    append stored entries <= T; tiles whose 4th entry <= T
//                    are rescanned scalar-wise (rare, exact, dedup'd)
//  6) merge_rerank:  one WAVE per query: coalesced row gather + fp64 butterfly
//                    dot; rank-count top-16 + cosine weights
//  7) yh_kernel:     MFMA fp16: Yh[p][0:256]=feat@W1^T, Yh[p][256:512]=feat@W2^T+b
//  8) final_kernel:  out[b][c][i] = max_k w_k*(Yh[nk][c]+Yh[m][256+c])

#define B_ 2
#define C_ 256
#define N_ 4096
#define K_ 16
#define SCAP 128
#define INF_F 3.0e38f

typedef _Float16 f16x8 __attribute__((ext_vector_type(8)));
typedef float    f32x4 __attribute__((ext_vector_type(4)));

// async global->LDS, 16B per lane; LDS dest wave-uniform base + lane*16
#define GL16(gp, lp)                                                        \
    __builtin_amdgcn_global_load_lds(                                       \
        (const __attribute__((address_space(1))) void*)(gp),                \
        (__attribute__((address_space(3))) void*)(lp), 16, 0, 0)

// ---------------- 1) squared norms ----------------
__global__ void sq_kernel(const float* __restrict__ x,
                          float* __restrict__ sq32, double* __restrict__ sq64) {
    int p = blockIdx.x * 256 + threadIdx.x;           // 0..8191
    int b = p >> 12, i = p & 4095;
    const float* xb = x + ((size_t)b << 20) + i;
    double acc = 0.0;
    #pragma unroll 8
    for (int c = 0; c < C_; ++c) {
        double v = (double)xb[(size_t)c << 12];
        acc = fma(v, v, acc);
    }
    sq64[p] = acc;
    sq32[p] = (float)acc;
}

// ---------------- 2) transpose x -> xt fp32 + xh fp16 ----------------
__global__ void xt_kernel(const float* __restrict__ x, float* __restrict__ xt,
                          _Float16* __restrict__ xh) {
    __shared__ float tile[64][65];
    int i0 = blockIdx.x * 64;
    int c0 = blockIdx.y * 64;
    int b  = blockIdx.z;
    const float* xb = x + ((size_t)b << 20);
    int tid = threadIdx.x;
    int tx = tid & 63, tyy = tid >> 6;
    for (int r = tyy; r < 64; r += 4)
        tile[r][tx] = xb[(size_t)(c0 + r) * N_ + i0 + tx];
    __syncthreads();
    float*    xtb = xt + ((size_t)b << 20);
    _Float16* xhb = xh + ((size_t)b << 20);
    for (int r = tyy; r < 64; r += 4) {
        float v = tile[tx][r];
        xtb[(size_t)(i0 + r) * C_ + c0 + tx] = v;
        xhb[(size_t)(i0 + r) * C_ + c0 + tx] = (_Float16)v;
    }
}

// ---------------- 3) W -> fp16 in [outchan][c] layout ----------------
__global__ void wh_kernel(const float* __restrict__ W, _Float16* __restrict__ Wh) {
    int r = blockIdx.x;                               // 0..511
    int c = threadIdx.x;                              // 0..255
    float v = (r < 256) ? W[(size_t)r * 512 + c]
                        : W[(size_t)(r - 256) * 512 + 256 + c];
    Wh[(size_t)r * 256 + c] = (_Float16)v;
}

// ---------------- 4) single-sweep MFMA gram + per-tile top-4 (LDS scan) ----------------
__launch_bounds__(256, 2)
__global__ void dist_kernel(const _Float16* __restrict__ xh,
                            const float* __restrict__ sq32,
                            float* __restrict__ t4v,
                            unsigned short* __restrict__ t4j) {
    __shared__ alignas(16) _Float16 As[2][128][64];
    __shared__ alignas(16) _Float16 Bs[2][128][64];

    int jt = blockIdx.x, it = blockIdx.y, b = blockIdx.z;
    int tid = threadIdx.x;
    int w = tid >> 6, l = tid & 63;
    int wr = w >> 1, wc = w & 1;
    int lr = l & 15, lg = l >> 4;
    const _Float16* xb = xh + ((size_t)b << 20);
    int rA0 = it * 128, rB0 = jt * 128;

    int rsub = l >> 3;                          // 0..7
    int cbyte = (l & 7) << 4;                   // 0..112 bytes

    auto STAGE = [&](int bf, int k0) {
        #pragma unroll
        for (int tt = 0; tt < 4; ++tt) {
            int rloc = w * 32 + tt * 8 + rsub;                 // 0..127
            int srch = (cbyte ^ ((rloc & 7) << 4)) >> 1;       // halfs
            GL16(xb + (size_t)(rA0 + rloc) * C_ + k0 + srch, &As[bf][w * 32 + tt * 8][0]);
            GL16(xb + (size_t)(rB0 + rloc) * C_ + k0 + srch, &Bs[bf][w * 32 + tt * 8][0]);
        }
    };

    f32x4 acc[4][4];
    #pragma unroll
    for (int mi = 0; mi < 4; ++mi)
        #pragma unroll
        for (int ni = 0; ni < 4; ++ni)
            acc[mi][ni] = (f32x4){0.f, 0.f, 0.f, 0.f};

    STAGE(0, 0);
    __syncthreads();
    #pragma unroll
    for (int kt = 0; kt < 4; ++kt) {
        int cur = kt & 1;
        if (kt < 3) STAGE(cur ^ 1, (kt + 1) * 64);
        #pragma unroll
        for (int kk = 0; kk < 2; ++kk) {
            int kh = kk * 32 + lg * 8;
            f16x8 af[4], bf4[4];
            #pragma unroll
            for (int mi = 0; mi < 4; ++mi) {
                int r = wr * 64 + mi * 16 + lr;
                af[mi] = *(const f16x8*)&As[cur][r][kh ^ ((r & 7) << 3)];
            }
            #pragma unroll
            for (int ni = 0; ni < 4; ++ni) {
                int r = wc * 64 + ni * 16 + lr;
                bf4[ni] = *(const f16x8*)&Bs[cur][r][kh ^ ((r & 7) << 3)];
            }
            #pragma unroll
            for (int mi = 0; mi < 4; ++mi)
                #pragma unroll
                for (int ni = 0; ni < 4; ++ni)
                    acc[mi][ni] = __builtin_amdgcn_mfma_f32_16x16x32_f16(
                        af[mi], bf4[ni], acc[mi][ni], 0, 0, 0);
        }
        __syncthreads();                        // last iter: all LDS reads retired
    }

    // ---- epilogue: per-row top-4 of this wave's 64x64 V block ----
    int bN = b << 12;
    float sjv[4];
    #pragma unroll
    for (int ni = 0; ni < 4; ++ni)
        sjv[ni] = sq32[bN + jt * 128 + wc * 64 + ni * 16 + lr];

    float* vb = (float*)&As[0][0][0] + w * 4096;        // 16KB per wave
    #pragma unroll
    for (int mi = 0; mi < 4; ++mi)
        #pragma unroll
        for (int ni = 0; ni < 4; ++ni) {
            int c  = ni * 16 + lr;
            int rb = (mi * 16 + lg * 4) ^ ((c & 7) << 3);
            f32x4 vv;
            #pragma unroll
            for (int r = 0; r < 4; ++r)
                vv[r] = sjv[ni] - 2.0f * acc[mi][ni][r];
            *(f32x4*)&vb[c * 64 + rb] = vv;             // V^T, swizzled
        }
    asm volatile("s_waitcnt lgkmcnt(0)" ::: "memory");  // wave-local visibility
    __builtin_amdgcn_sched_barrier(0);

    float v0 = INF_F, v1 = INF_F, v2 = INF_F, v3 = INF_F;
    int j0 = 0, j1 = 0, j2 = 0, j3 = 0;
    #pragma unroll
    for (int c = 0; c < 64; ++c) {
        float v = vb[c * 64 + (l ^ ((c & 7) << 3))];
        bool in = v < v3;                               // strict: lowest-c wins ties
        v3 = in ? v : v3;  j3 = in ? c : j3;
        { bool s = v3 < v2; float t = v2; int tj2 = j2;
          v2 = s ? v3 : v2; v3 = s ? t : v3; j2 = s ? j3 : j2; j3 = s ? tj2 : j3; }
        { bool s = v2 < v1; float t = v1; int tj2 = j1;
          v1 = s ? v2 : v1; v2 = s ? t : v2; j1 = s ? j2 : j1; j2 = s ? tj2 : j2; }
        { bool s = v1 < v0; float t = v0; int tj2 = j0;
          v0 = s ? v1 : v0; v1 = s ? t : v1; j0 = s ? j1 : j0; j1 = s ? tj2 : j1; }
    }
    int tj = jt * 2 + wc;
    int q  = bN + it * 128 + wr * 64 + l;
    int jb = jt * 128 + wc * 64;
    size_t ob = ((size_t)tj * 8192 + q) * 4;            // [tile][query] layout
    *(float4*)&t4v[ob] = make_float4(v0, v1, v2, v3);
    ushort4 js;
    js.x = (unsigned short)(jb + j0); js.y = (unsigned short)(jb + j1);
    js.z = (unsigned short)(jb + j2); js.w = (unsigned short)(jb + j3);
    *(ushort4*)&t4j[ob] = js;
}

// ---------------- 5) collect: threshold + candidate append (+rare rescan) ----------------
__global__ void collect_kernel(const float* __restrict__ t4v,
                               const unsigned short* __restrict__ t4j,
                               const _Float16* __restrict__ xh,
                               const float* __restrict__ sq32,
                               int* __restrict__ svj, int* __restrict__ cntg) {
    __shared__ float sv[4][64];
    __shared__ float sT[4];
    int tid = threadIdx.x;
    int wv4 = tid >> 6, l = tid & 63;
    int q = blockIdx.x * 4 + wv4;                 // global query 0..8191
    int b = q >> 12, bN = b << 12;

    size_t base = ((size_t)l * 8192 + q) * 4;
    float4 vf = *(const float4*)&t4v[base];
    ushort4 uf = *(const ushort4*)&t4j[base];
    float v[4] = {vf.x, vf.y, vf.z, vf.w};
    int  j4[4] = {(int)uf.x, (int)uf.y, (int)uf.z, (int)uf.w};

    sv[wv4][l] = v[0];
    __syncthreads();
    int rank = 0;
    for (int o = 0; o < 64; ++o) {
        float ov = sv[wv4][o];
        rank += (ov < v[0]) || (ov == v[0] && o < l);
    }
    if (rank == 19) sT[wv4] = v[0];
    __syncthreads();
    float T5 = sT[wv4] + 0.5f;

    int cnt = 0;
    #pragma unroll
    for (int k = 0; k < 4; ++k) cnt += (v[k] <= T5) ? 1 : 0;   // sorted -> prefix
    bool flag = (v[3] <= T5);                     // possible hidden 5th

    int off = cnt;
    #pragma unroll
    for (int s = 1; s < 64; s <<= 1) {
        int n = __shfl_up(off, s);
        if (l >= s) off += n;
    }
    int pos = off - cnt;
    int total = __shfl(off, 63);
    for (int k = 0; k < cnt; ++k)
        if (pos + k < SCAP) svj[(size_t)q * SCAP + pos + k] = j4[k];

    unsigned long long fb = __ballot(flag);
    if (fb != 0ULL) {                             // rare exact-completion path
        const _Float16* qrow = xh + ((size_t)q << 8);
        while (fb) {
            int tf = (int)__ffsll(fb) - 1; fb &= fb - 1;
            int jg = tf * 64 + l;                 // batch-local col
            const _Float16* jrow = xh + (((size_t)(bN + jg)) << 8);
            float dot = 0.f;
            #pragma unroll 4
            for (int c = 0; c < C_; c += 8) {
                f16x8 a = *(const f16x8*)(qrow + c);
                f16x8 bb = *(const f16x8*)(jrow + c);
                #pragma unroll
                for (int e = 0; e < 8; ++e)
                    dot = fmaf((float)a[e], (float)bb[e], dot);
            }
            float vv = sq32[bN + jg] - 2.0f * dot;
            bool dup = false;
            size_t tb = ((size_t)tf * 8192 + q) * 4;
            #pragma unroll
            for (int k = 0; k < 4; ++k) dup |= ((int)t4j[tb + k] == jg);
            bool add = (vv <= T5 + 0.0625f) && !dup;
            int o2 = add ? 1 : 0;
            #pragma unroll
            for (int s = 1; s < 64; s <<= 1) {
                int n = __shfl_up(o2, s);
                if (l >= s) o2 += n;
            }
            int p2 = total + o2 - (add ? 1 : 0);
            if (add && p2 < SCAP) svj[(size_t)q * SCAP + p2] = jg;
            total += __shfl(o2, 63);
        }
    }
    if (l == 0) cntg[q] = total < SCAP ? total : SCAP;
}

// ---------------- 6) fp64 re-rank: one wave per query, coalesced gather ----------------
// block 256 = 4 waves = 4 queries; grid 2048. Lane l holds q-row float4 [4l..4l+3].
// Per survivor: coalesced 1KB row read + fp64 butterfly reduce (pairs overlap).
// Selection: rank-count over d values in LDS, rank<16 writes directly.
__global__ void merge_rerank(const int* __restrict__ svj, const int* __restrict__ cntg,
                             const float* __restrict__ xt,
                             const double* __restrict__ sq64,
                             int* __restrict__ nidx, float* __restrict__ wgt) {
    __shared__ double ds[4][SCAP];
    int tid = threadIdx.x;
    int wv = tid >> 6, l = tid & 63;
    int q = (blockIdx.x << 2) + wv;
    int b = q >> 12, bN = b << 12;
    int cnt = cntg[q]; if (cnt > SCAP) cnt = SCAP;
    size_t sbase = (size_t)q * SCAP;
    int l4 = l << 2;

    float4 qf = *(const float4*)&xt[((size_t)q << 8) + l4];

    for (int cc = 0; cc < cnt; cc += 2) {
        bool has1 = (cc + 1) < cnt;
        int n0 = bN + svj[sbase + cc];
        int n1 = has1 ? bN + svj[sbase + cc + 1] : n0;
        float4 r0 = *(const float4*)&xt[((size_t)n0 << 8) + l4];
        float4 r1 = *(const float4*)&xt[((size_t)n1 << 8) + l4];
        double p0 = fma((double)qf.x, (double)r0.x,
                    fma((double)qf.y, (double)r0.y,
                    fma((double)qf.z, (double)r0.z,
                        (double)qf.w * (double)r0.w)));
        double p1 = fma((double)qf.x, (double)r1.x,
                    fma((double)qf.y, (double)r1.y,
                    fma((double)qf.z, (double)r1.z,
                        (double)qf.w * (double)r1.w)));
        #pragma unroll
        for (int s = 1; s < 64; s <<= 1) {
            p0 += __shfl_xor(p0, s);
            p1 += __shfl_xor(p1, s);
        }
        if (l == 0) {
            ds[wv][cc] = sq64[n0] - 2.0 * p0;
            if (has1) ds[wv][cc + 1] = sq64[n1] - 2.0 * p1;
        }
    }
    __syncthreads();

    double rdm = sqrt(sq64[q]);
    for (int p = l; p < cnt; p += 64) {
        double d = ds[wv][p];
        int rank = 0;
        for (int o = 0; o < cnt; ++o) {
            double od = ds[wv][o];
            rank += (od < d) || (od == d && o < p);
        }
        if (rank < K_) {
            int n = bN + svj[sbase + p];
            double sqn = sq64[n];
            double dot = 0.5 * (sqn - d);
            double w = dot / (sqrt(sqn) * rdm);
            nidx[q * K_ + rank] = n;
            wgt[q * K_ + rank]  = (float)w;
        }
    }
}

// ---------------- 7) Yh via MFMA fp16: Yh[p][0:256]=Y1, [256:512]=Y2+b ----------------
__launch_bounds__(256, 2)
__global__ void yh_kernel(const _Float16* __restrict__ xh,
                          const _Float16* __restrict__ Wh,
                          const float* __restrict__ bias,
                          _Float16* __restrict__ Yh) {
    __shared__ alignas(16) _Float16 As[2][128][64];
    __shared__ alignas(16) _Float16 Bs[2][128][64];

    int jt = blockIdx.x, it = blockIdx.y;
    int tid = threadIdx.x;
    int w = tid >> 6, l = tid & 63;
    int wr = w >> 1, wc = w & 1;
    int lr = l & 15, lg = l >> 4;
    int rA0 = it * 128, rB0 = jt * 128;

    int rsub = l >> 3;
    int cbyte = (l & 7) << 4;

    auto STAGE = [&](int bf, int k0) {
        #pragma unroll
        for (int tt = 0; tt < 4; ++tt) {
            int rloc = w * 32 + tt * 8 + rsub;
            int srch = (cbyte ^ ((rloc & 7) << 4)) >> 1;
            GL16(xh + (size_t)(rA0 + rloc) * C_ + k0 + srch, &As[bf][w * 32 + tt * 8][0]);
            GL16(Wh + (size_t)(rB0 + rloc) * C_ + k0 + srch, &Bs[bf][w * 32 + tt * 8][0]);
        }
    };

    f32x4 acc[4][4];
    #pragma unroll
    for (int mi = 0; mi < 4; ++mi)
        #pragma unroll
        for (int ni = 0; ni < 4; ++ni)
            acc[mi][ni] = (f32x4){0.f, 0.f, 0.f, 0.f};

    STAGE(0, 0);
    __syncthreads();
    #pragma unroll
    for (int kt = 0; kt < 4; ++kt) {
        int cur = kt & 1;
        if (kt < 3) STAGE(cur ^ 1, (kt + 1) * 64);
        #pragma unroll
        for (int kk = 0; kk < 2; ++kk) {
            int kh = kk * 32 + lg * 8;
            f16x8 af[4], bf4[4];
            #pragma unroll
            for (int mi = 0; mi < 4; ++mi) {
                int r = wr * 64 + mi * 16 + lr;
                af[mi] = *(const f16x8*)&As[cur][r][kh ^ ((r & 7) << 3)];
            }
            #pragma unroll
            for (int ni = 0; ni < 4; ++ni) {
                int r = wc * 64 + ni * 16 + lr;
                bf4[ni] = *(const f16x8*)&Bs[cur][r][kh ^ ((r & 7) << 3)];
            }
            #pragma unroll
            for (int mi = 0; mi < 4; ++mi)
                #pragma unroll
                for (int ni = 0; ni < 4; ++ni)
                    acc[mi][ni] = __builtin_amdgcn_mfma_f32_16x16x32_f16(
                        af[mi], bf4[ni], acc[mi][ni], 0, 0, 0);
        }
        __syncthreads();
    }

    int colbase = jt * 128 + wc * 64;             // wave-uniform
    bool isY2 = colbase >= 256;
    float bv[4];
    #pragma unroll
    for (int ni = 0; ni < 4; ++ni)
        bv[ni] = isY2 ? bias[colbase - 256 + ni * 16 + lr] : 0.f;

    #pragma unroll
    for (int mi = 0; mi < 4; ++mi)
        #pragma unroll
        for (int r = 0; r < 4; ++r) {
            int p = it * 128 + wr * 64 + mi * 16 + lg * 4 + r;
            #pragma unroll
            for (int ni = 0; ni < 4; ++ni)
                Yh[(size_t)p * 512 + colbase + ni * 16 + lr] =
                    (_Float16)(acc[mi][ni][r] + bv[ni]);
        }
}

// ---------------- 8) weighted max epilogue (fp16 Yh) ----------------
__global__ void final_kernel(const _Float16* __restrict__ Yh,
                             const int* __restrict__ nidx, const float* __restrict__ wgt,
                             float* __restrict__ out) {
    __shared__ int   snk[K_];
    __shared__ float swt[K_];
    int m = blockIdx.x;
    int c = threadIdx.x;
    if (c < K_) { snk[c] = nidx[m * K_ + c]; swt[c] = wgt[m * K_ + c]; }
    __syncthreads();
    float y2 = (float)Yh[(size_t)m * 512 + 256 + c];
    float acc = -INF_F;
    #pragma unroll
    for (int k = 0; k < K_; ++k) {
        float v = swt[k] * ((float)Yh[(size_t)snk[k] * 512 + c] + y2);
        acc = fmaxf(acc, v);
    }
    int b = m >> 12, i = m & 4095;
    out[(((size_t)b << 8) + c) * N_ + i] = acc;
}

extern "C" void kernel_launch(void* const* d_in, const int* in_sizes, int n_in,
                              void* d_out, int out_size, void* d_ws, size_t ws_size,
                              hipStream_t stream) {
    const float* x    = (const float*)d_in[0];
    const float* W    = (const float*)d_in[1];
    const float* bias = (const float*)d_in[2];
    float* out = (float*)d_out;

    float* ws = (float*)d_ws;
    size_t off = 0;
    float*  sq32 = ws + off;            off += 8192;
    double* sq64 = (double*)(ws + off); off += 16384;
    float*  wgt  = ws + off;            off += 131072;
    int*    nidx = (int*)(ws + off);    off += 131072;
    int*    cntg = (int*)(ws + off);    off += 8192;
    size_t svj_off = off;
    int*    svj  = (int*)(ws + off);    off += 1048576;    // 8192 x 128
    float*  xt   = ws + off;            off += 2097152;    // 8 MB
    _Float16* xh = (_Float16*)(ws + off); off += 1048576;  // 4 MB (2M halfs)
    float*  t4v  = ws + off;            off += 2097152;    // 64 x 8192 x 4 f32
    unsigned short* t4j = (unsigned short*)(ws + off); off += 1048576;
    _Float16* Wh = (_Float16*)(ws + off); off += 65536;    // 512x256 halfs
    // Yh (8192x512 fp16 = 2M f-equiv) overlays svj+xt (dead after merge)
    _Float16* Yh = (_Float16*)(ws + svj_off);

    sq_kernel<<<32, 256, 0, stream>>>(x, sq32, sq64);
    xt_kernel<<<dim3(64, 4, 2), 256, 0, stream>>>(x, xt, xh);
    wh_kernel<<<512, 256, 0, stream>>>(W, Wh);

    dist_kernel<<<dim3(32, 32, 2), 256, 0, stream>>>(xh, sq32, t4v, t4j);
    collect_kernel<<<2048, 256, 0, stream>>>(t4v, t4j, xh, sq32, svj, cntg);

    merge_rerank<<<2048, 256, 0, stream>>>(svj, cntg, xt, sq64, nidx, wgt);
    yh_kernel<<<dim3(4, 64, 1), 256, 0, stream>>>(xh, Wh, bias, Yh);
    final_kernel<<<8192, 256, 0, stream>>>(Yh, nidx, wgt, out);
}